// Round 9
// baseline (138.210 us; speedup 1.0000x reference)
//
#include <hip/hip_runtime.h>
#include <hip/hip_fp16.h>
#include <math.h>

static constexpr int BATCH = 2048;

// ---------------------------------------------------------------------------
// ws layout:
//   bytes [0, 910336): f16 step-major weight stream, 127 steps x 7168 B.
//     Per step (lane L = 0..63):
//       A  (P2 lo rows t0..3)  at    0 + 32L: u32x8 = [t0 s0s1][t0 s2s3][t1 ..]..[t3 ..]
//       B1 (P1 col lo|hi)      at 2048 + 16L: u32x4 = [s0s1][s2s3][h0h1][h2h3]
//       B2 (P2 hi rows t0..3)  at 3072 + 32L: u32x8
//       B3 (P3 rows t0..3)     at 5120 + 32L: u32x8 = [t0 o0o1][t0 o2o3][t1 ..]..
//   floats [227584, +2048): P2X[4][512]  extra-unit (508+t) rows, slot-ordered
//   floats [229632, +1024): P3X[4][256]
// slot s = 4i+t <-> unit 127t+i (i<127) or 508+t (i=127); deg(unit j)=j%127
// (j<508) else j-508.  Degree-i units: lane i&63, regs {t} (i<64) / {4+t}.
//
// DEAD-DESTINATION CLAMP (round 9): every sub-block is destination-indexed;
// a destination of degree d is never read after step d.  Dead lanes' load
// addresses are clamped onto the first live lane's address (v_max, NO branch:
// load count constant, vmcnt countable — round-7 lesson), so the TA coalesces
// them into ~1 segment instead of streaming dead rows.  Garbage lands only in
// dead state slots (proven safe in rounds 7/8).
// ---------------------------------------------------------------------------
static constexpr int STEP_BYTES = 7168;
static constexpr int X2_FOFF    = 227584;           // floats
static constexpr int X3_FOFF    = X2_FOFF + 2048;   // floats

__device__ __forceinline__ int sigmaInvU(int s) {
    int i = s >> 2, t = s & 3;
    return (i == 127) ? (508 + t) : (127 * t + i);
}
__device__ __forceinline__ int degU(int x) {
    return (x < 508) ? (x % 127) : (x - 508);
}
__device__ __forceinline__ int imax(int a, int b) { return a > b ? a : b; }
__device__ __forceinline__ float fc(float4 v, int k) {
    return k == 0 ? v.x : k == 1 ? v.y : k == 2 ? v.z : v.w;
}
__device__ __forceinline__ unsigned uc(uint4 v, int k) {
    return k == 0 ? v.x : k == 1 ? v.y : k == 2 ? v.z : v.w;
}
__device__ __forceinline__ float hlo(unsigned u) {
    return __half2float(__ushort_as_half((unsigned short)(u & 0xffffu)));
}
__device__ __forceinline__ float hhi(unsigned u) {
    return __half2float(__ushort_as_half((unsigned short)(u >> 16)));
}
// Uniform-lane broadcast via v_readlane (VALU pipe, SGPR result).
__device__ __forceinline__ float rl(float v, int l) {
    return __int_as_float(__builtin_amdgcn_readlane(__float_as_int(v), l));
}

// ---------------------------------------------------------------------------
// Prep: unchanged from round 8 (passing).  Each thread produces one 16B
// stream chunk; tail threads fill the f32 extra-unit tables.
// ---------------------------------------------------------------------------
__global__ __launch_bounds__(256) void maf_prep(
    const float* __restrict__ W1, const float* __restrict__ W2,
    const float* __restrict__ W3, float* __restrict__ ws)
{
    const int NCH = 127 * 448;          // 16B chunks in the stream
    int q = blockIdx.x * 256 + threadIdx.x;
    if (q < NCH) {
        int i = q / 448, rem = q % 448;
        unsigned short h[8];
        if (rem < 128) {                // A: P2 lo
            int L = rem >> 1, f = rem & 1;
#pragma unroll
            for (int e = 0; e < 8; ++e) {
                int t = 2 * f + (e >> 2), c = e & 3;
                int cu = 127 * c + L;                    // unit of slot 4L+c
                float v = (L >= i) ? W2[cu * 512 + 127 * t + i] : 0.f;
                h[e] = __half_as_ushort(__float2half(v));
            }
        } else if (rem < 192) {         // B1: P1 col, lo|hi interleaved
            int L = rem - 128;
#pragma unroll
            for (int e = 0; e < 8; ++e) {
                int s = (e < 4) ? (4 * L + e) : (256 + 4 * L + (e - 4));
                int cu = sigmaInvU(s);
                int dg = degU(cu);
                float v = (dg >= i) ? W1[cu * 128 + i] : 0.f;
                h[e] = __half_as_ushort(__float2half(v));
            }
        } else if (rem < 320) {         // B2: P2 hi
            int idx = rem - 192, L = idx >> 1, f = idx & 1;
#pragma unroll
            for (int e = 0; e < 8; ++e) {
                int t = 2 * f + (e >> 2), c = e & 3;
                int cu = sigmaInvU(256 + 4 * L + c);
                int dg = degU(cu);
                float v = (dg >= i) ? W2[cu * 512 + 127 * t + i] : 0.f;
                h[e] = __half_as_ushort(__float2half(v));
            }
        } else {                        // B3: P3
            int idx = rem - 320, L = idx >> 1, f = idx & 1;
#pragma unroll
            for (int e = 0; e < 8; ++e) {
                int t = 2 * f + (e >> 2), c = e & 3;
                int o = 4 * L + c;
                float v = ((o & 127) - 1 >= i) ? W3[o * 512 + 127 * t + i] : 0.f;
                h[e] = __half_as_ushort(__float2half(v));
            }
        }
        uint4 o4;
        o4.x = (unsigned)h[0] | ((unsigned)h[1] << 16);
        o4.y = (unsigned)h[2] | ((unsigned)h[3] << 16);
        o4.z = (unsigned)h[4] | ((unsigned)h[5] << 16);
        o4.w = (unsigned)h[6] | ((unsigned)h[7] << 16);
        *(uint4*)((char*)ws + (size_t)q * 16) = o4;
    } else if (q < NCH + 768) {         // extra-unit f32 tables
        int e = q - NCH;
        if (e < 512) {                  // P2X[t][512]
            int t = e >> 7, s0 = (e & 127) * 4;
            float4 o4;
#pragma unroll
            for (int c = 0; c < 4; ++c) {
                int cu = sigmaInvU(s0 + c);
                float v = (degU(cu) >= t) ? W2[cu * 512 + 508 + t] : 0.f;
                if (c == 0) o4.x = v; else if (c == 1) o4.y = v;
                else if (c == 2) o4.z = v; else o4.w = v;
            }
            *(float4*)(ws + X2_FOFF + t * 512 + s0) = o4;
        } else {                        // P3X[t][256]
            int e2 = e - 512;
            int t = e2 >> 6, o0 = (e2 & 63) * 4;
            float4 o4;
#pragma unroll
            for (int c = 0; c < 4; ++c) {
                int o = o0 + c;
                float v = ((o & 127) - 1 >= t) ? W3[o * 512 + 508 + t] : 0.f;
                if (c == 0) o4.x = v; else if (c == 1) o4.y = v;
                else if (c == 2) o4.z = v; else o4.w = v;
            }
            *(float4*)(ws + X3_FOFF + t * 256 + o0) = o4;
        }
    }
}

// ---------------------------------------------------------------------------
// Double-buffered NAMED uint4 weight registers (7 per set).  Loads are
// unconditional (wave-uniform count, countable vmcnt); dead lanes CLAMP their
// addresses (v_max) onto the first live lane.  sched_barrier(0) pins issue
// order (round-5/6 lesson).
// ---------------------------------------------------------------------------
#define DECL_WSET(P) \
    uint4 P##a0{}, P##a1{}, P##b0{}, P##b1{}, P##b2{}, P##b3{}, P##b4{};

// Load step N's weights, N in [0,63].
#define LOADS_LO(P, N) do { \
    const int aOff  = imax(ln, (N)) << 5; \
    const int b3Off = 5120 + ((l32 + imax(l31, (N) >> 2)) << 5); \
    P##a0 = *(const uint4*)(sb + aOff); \
    P##a1 = *(const uint4*)(sb + aOff + 16); \
    P##b0 = *(const uint4*)(sb + offB1n); \
    P##b1 = *(const uint4*)(sb + offB2n); \
    P##b2 = *(const uint4*)(sb + offB2n + 16); \
    P##b3 = *(const uint4*)(sb + b3Off); \
    P##b4 = *(const uint4*)(sb + b3Off + 16); \
    sb += STEP_BYTES; \
    __builtin_amdgcn_sched_barrier(0); \
} while (0)

// Load step N's weights, N in [64,126]: lo-half destinations all dead.
#define LOADS_HI(P, N) do { \
    const int mj    = imax(ln, (N) - 64); \
    const int b3Off = 5120 + ((l32 + imax(l31, (N) >> 2)) << 5); \
    P##b0 = *(const uint4*)(sb + 2048 + (mj << 4)); \
    P##b1 = *(const uint4*)(sb + 3072 + (mj << 5)); \
    P##b2 = *(const uint4*)(sb + 3072 + (mj << 5) + 16); \
    P##b3 = *(const uint4*)(sb + b3Off); \
    P##b4 = *(const uint4*)(sb + b3Off + 16); \
    sb += STEP_BYTES; \
    __builtin_amdgcn_sched_barrier(0); \
} while (0)

#define L2ONE(P, T, LO) do { \
    const float hA = rl(fmaxf(LO ? h1A[T] : h1A[4 + (T)], 0.f), l0); \
    const float hB = rl(fmaxf(LO ? h1B[T] : h1B[4 + (T)], 0.f), l0); \
    if (LO) { \
        const unsigned m0 = uc((T) < 2 ? P##a0 : P##a1, 2 * ((T) & 1)); \
        const unsigned m1 = uc((T) < 2 ? P##a0 : P##a1, 2 * ((T) & 1) + 1); \
        h2A[0] = fmaf(hlo(m0), hA, h2A[0]); h2A[1] = fmaf(hhi(m0), hA, h2A[1]); \
        h2A[2] = fmaf(hlo(m1), hA, h2A[2]); h2A[3] = fmaf(hhi(m1), hA, h2A[3]); \
        h2B[0] = fmaf(hlo(m0), hB, h2B[0]); h2B[1] = fmaf(hhi(m0), hB, h2B[1]); \
        h2B[2] = fmaf(hlo(m1), hB, h2B[2]); h2B[3] = fmaf(hhi(m1), hB, h2B[3]); \
    } \
    const unsigned n0 = uc((T) < 2 ? P##b1 : P##b2, 2 * ((T) & 1)); \
    const unsigned n1 = uc((T) < 2 ? P##b1 : P##b2, 2 * ((T) & 1) + 1); \
    h2A[4] = fmaf(hlo(n0), hA, h2A[4]); h2A[5] = fmaf(hhi(n0), hA, h2A[5]); \
    h2A[6] = fmaf(hlo(n1), hA, h2A[6]); h2A[7] = fmaf(hhi(n1), hA, h2A[7]); \
    h2B[4] = fmaf(hlo(n0), hB, h2B[4]); h2B[5] = fmaf(hhi(n0), hB, h2B[5]); \
    h2B[6] = fmaf(hlo(n1), hB, h2B[6]); h2B[7] = fmaf(hhi(n1), hB, h2B[7]); \
} while (0)

#define L3ONE(P, T, LO) do { \
    const float gA = rl(fmaxf(LO ? h2A[T] : h2A[4 + (T)], 0.f), l0); \
    const float gB = rl(fmaxf(LO ? h2B[T] : h2B[4 + (T)], 0.f), l0); \
    const unsigned p0 = uc((T) < 2 ? P##b3 : P##b4, 2 * ((T) & 1)); \
    const unsigned p1 = uc((T) < 2 ? P##b3 : P##b4, 2 * ((T) & 1) + 1); \
    zA[0] = fmaf(hlo(p0), gA, zA[0]); zA[1] = fmaf(hhi(p0), gA, zA[1]); \
    zA[2] = fmaf(hlo(p1), gA, zA[2]); zA[3] = fmaf(hhi(p1), gA, zA[3]); \
    zB[0] = fmaf(hlo(p0), gB, zB[0]); zB[1] = fmaf(hhi(p0), gB, zB[1]); \
    zB[2] = fmaf(hlo(p1), gB, zB[2]); zB[3] = fmaf(hhi(p1), gB, zB[3]); \
} while (0)

// One inversion step.  I may be runtime; LO must be a literal == ((I) < 64).
#define STEP(I, P, LO) do { \
    const int l0 = (I) & 63, lm = (I) >> 2, rs = (I) & 3; \
    float zsA = rs == 0 ? zA[0] : rs == 1 ? zA[1] : rs == 2 ? zA[2] : zA[3]; \
    float zsB = rs == 0 ? zB[0] : rs == 1 ? zB[1] : rs == 2 ? zB[2] : zB[3]; \
    const float muA = rl(zsA, lm), sgA = rl(zsA, 32 + lm); \
    const float muB = rl(zsB, lm), sgB = rl(zsB, 32 + lm); \
    const float uiA = rl(LO ? uA0 : uA1, l0); \
    const float uiB = rl(LO ? uB0 : uB1, l0); \
    const float xiA = fmaf(uiA, __expf(sgA), muA); \
    const float xiB = fmaf(uiB, __expf(sgB), muB); \
    ldA += sgA; ldB += sgB; \
    if (lane == l0) { \
        if (LO) { xA0 = xiA; xB0 = xiB; } else { xA1 = xiA; xB1 = xiB; } \
    } \
    if (LO) { \
        h1A[0] = fmaf(hlo(P##b0.x), xiA, h1A[0]); \
        h1A[1] = fmaf(hhi(P##b0.x), xiA, h1A[1]); \
        h1A[2] = fmaf(hlo(P##b0.y), xiA, h1A[2]); \
        h1A[3] = fmaf(hhi(P##b0.y), xiA, h1A[3]); \
        h1B[0] = fmaf(hlo(P##b0.x), xiB, h1B[0]); \
        h1B[1] = fmaf(hhi(P##b0.x), xiB, h1B[1]); \
        h1B[2] = fmaf(hlo(P##b0.y), xiB, h1B[2]); \
        h1B[3] = fmaf(hhi(P##b0.y), xiB, h1B[3]); \
    } \
    h1A[4] = fmaf(hlo(P##b0.z), xiA, h1A[4]); \
    h1A[5] = fmaf(hhi(P##b0.z), xiA, h1A[5]); \
    h1A[6] = fmaf(hlo(P##b0.w), xiA, h1A[6]); \
    h1A[7] = fmaf(hhi(P##b0.w), xiA, h1A[7]); \
    h1B[4] = fmaf(hlo(P##b0.z), xiB, h1B[4]); \
    h1B[5] = fmaf(hhi(P##b0.z), xiB, h1B[5]); \
    h1B[6] = fmaf(hlo(P##b0.w), xiB, h1B[6]); \
    h1B[7] = fmaf(hhi(P##b0.w), xiB, h1B[7]); \
    L2ONE(P, 0, LO); L2ONE(P, 1, LO); L2ONE(P, 2, LO); L2ONE(P, 3, LO); \
    if (LO && (I) < 4) { \
        float eA = (I) == 0 ? h1A[4] : (I) == 1 ? h1A[5] : (I) == 2 ? h1A[6] : h1A[7]; \
        float eB = (I) == 0 ? h1B[4] : (I) == 1 ? h1B[5] : (I) == 2 ? h1B[6] : h1B[7]; \
        const float hA = rl(fmaxf(eA, 0.f), 63); \
        const float hB = rl(fmaxf(eB, 0.f), 63); \
        const float4 wl = *(const float4*)(P2X + (I) * 512 + 4 * lane); \
        const float4 wh = *(const float4*)(P2X + (I) * 512 + 256 + 4 * lane); \
        _Pragma("unroll") for (int r = 0; r < 4; ++r) { \
            h2A[r] = fmaf(fc(wl, r), hA, h2A[r]); \
            h2B[r] = fmaf(fc(wl, r), hB, h2B[r]); \
            h2A[4 + r] = fmaf(fc(wh, r), hA, h2A[4 + r]); \
            h2B[4 + r] = fmaf(fc(wh, r), hB, h2B[4 + r]); } \
    } \
    L3ONE(P, 0, LO); L3ONE(P, 1, LO); L3ONE(P, 2, LO); L3ONE(P, 3, LO); \
    if (LO && (I) < 4) { \
        float eA = (I) == 0 ? h2A[4] : (I) == 1 ? h2A[5] : (I) == 2 ? h2A[6] : h2A[7]; \
        float eB = (I) == 0 ? h2B[4] : (I) == 1 ? h2B[5] : (I) == 2 ? h2B[6] : h2B[7]; \
        const float gA = rl(fmaxf(eA, 0.f), 63); \
        const float gB = rl(fmaxf(eB, 0.f), 63); \
        const float4 w4 = *(const float4*)(P3X + (I) * 256 + 4 * lane); \
        _Pragma("unroll") for (int s = 0; s < 4; ++s) { \
            zA[s] = fmaf(fc(w4, s), gA, zA[s]); \
            zB[s] = fmaf(fc(w4, s), gB, zB[s]); } \
    } \
} while (0)

__global__ __launch_bounds__(256, 1) void maf_inverse(
    const float* __restrict__ u, const float* __restrict__ b1,
    const float* __restrict__ b2, const float* __restrict__ b3,
    const float* __restrict__ ws, float* __restrict__ out)
{
    const float* P2X = ws + X2_FOFF;
    const float* P3X = ws + X3_FOFF;

    const int td = threadIdx.x;
    const int lane = td & 63;
    const int wid = td >> 6;
    const int rA = blockIdx.x * 8 + wid * 2;
    const int rB = rA + 1;

    // state: h slots {4*lane+r} (regs 0..3) / {256+4*lane+r} (regs 4..7);
    // z outputs {4*lane+s}.
    float h1A[8], h1B[8], h2A[8], h2B[8];
#pragma unroll
    for (int r = 0; r < 8; ++r) {
        int s = (r < 4) ? (4 * lane + r) : (256 + 4 * lane + (r - 4));
        int uu = sigmaInvU(s);
        float v1 = b1[uu], v2 = b2[uu];
        h1A[r] = v1; h1B[r] = v1; h2A[r] = v2; h2B[r] = v2;
    }
    float zA[4], zB[4];
    {
        const float4 bz = *(const float4*)(b3 + 4 * lane);
        zA[0] = bz.x; zA[1] = bz.y; zA[2] = bz.z; zA[3] = bz.w;
        zB[0] = bz.x; zB[1] = bz.y; zB[2] = bz.z; zB[3] = bz.w;
    }
    const float uA0 = u[rA * 128 + lane], uA1 = u[rA * 128 + 64 + lane];
    const float uB0 = u[rB * 128 + lane], uB1 = u[rB * 128 + 64 + lane];

    float xA0 = 0.f, xA1 = 0.f, xB0 = 0.f, xB1 = 0.f, ldA = 0.f, ldB = 0.f;

    // stream cursor (uniform) + precomputed per-lane offset pieces
    const char* sb = (const char*)ws;
    const int ln = lane, l31 = lane & 31, l32 = lane & 32;
    const int offB1n = 2048 + 16 * lane;   // B1, unclamped (lo phase)
    const int offB2n = 3072 + 32 * lane;   // B2, unclamped (lo phase)

    DECL_WSET(wa)
    DECL_WSET(wb)

    LOADS_LO(wa, 0);                 // step 0
#pragma unroll 1
    for (int i = 0; i < 62; i += 2) {        // steps 0..61
        LOADS_LO(wb, i + 1);
        STEP(i, wa, true);
        LOADS_LO(wa, i + 2);
        STEP(i + 1, wb, true);
    }
    // bridge: steps 62,63; loads 63 (lo), 64 (hi)
    LOADS_LO(wb, 63);
    STEP(62, wa, true);
    LOADS_HI(wa, 64);
    STEP(63, wb, true);
#pragma unroll 1
    for (int i = 64; i < 126; i += 2) {      // steps 64..125
        LOADS_HI(wb, i + 1);
        STEP(i, wa, false);
        LOADS_HI(wa, i + 2);
        STEP(i + 1, wb, false);
    }
    STEP(126, wa, false);

    // step 127: no propagation — x_127 and logdet only (mu=z[127], sg=z[255])
    {
        const float muA = rl(zA[3], 31), sgA = rl(zA[3], 63);
        const float muB = rl(zB[3], 31), sgB = rl(zB[3], 63);
        const float uiA = rl(uA1, 63), uiB = rl(uB1, 63);
        const float xiA = fmaf(uiA, __expf(sgA), muA);
        const float xiB = fmaf(uiB, __expf(sgB), muB);
        ldA += sgA; ldB += sgB;
        if (lane == 63) { xA1 = xiA; xB1 = xiB; }
    }

    out[rA * 128 + lane]      = xA0;
    out[rA * 128 + 64 + lane] = xA1;
    out[rB * 128 + lane]      = xB0;
    out[rB * 128 + 64 + lane] = xB1;
    if (lane == 0) {
        out[BATCH * 128 + rA] = ldA;
        out[BATCH * 128 + rB] = ldB;
    }
}

extern "C" void kernel_launch(void* const* d_in, const int* in_sizes, int n_in,
                              void* d_out, int out_size, void* d_ws, size_t ws_size,
                              hipStream_t stream)
{
    const float* u  = (const float*)d_in[0];
    const float* W1 = (const float*)d_in[1];
    const float* b1 = (const float*)d_in[2];
    const float* W2 = (const float*)d_in[3];
    const float* b2 = (const float*)d_in[4];
    const float* W3 = (const float*)d_in[5];
    const float* b3 = (const float*)d_in[6];
    // masks computed analytically in maf_prep; d_in[7..9] unused.
    float* ws  = (float*)d_ws;
    float* out = (float*)d_out;
    (void)ws_size; (void)in_sizes; (void)n_in; (void)out_size;

    maf_prep<<<226, 256, 0, stream>>>(W1, W2, W3, ws);
    maf_inverse<<<256, 256, 0, stream>>>(u, b1, b2, b3, ws, out);
}